// Round 5
// baseline (475.794 us; speedup 1.0000x reference)
//
#include <hip/hip_runtime.h>
#include <hip/hip_bf16.h>

// Problem constants (from reference)
#define NPTS   100000
#define NCENT  50000
#define NEDGE  1600000
#define DF     64      // feature dim
#define DP     3       // pos dim
#define DH     128     // hidden
#define DOUT   128     // out
#define TILE   128     // edges per block
#define LDA    104     // A-tile leading dim (ushorts), 96 + 8 pad
#define LDH    136     // H1-tile leading dim (ushorts), 128 + 8 pad
#define LDE    132     // Sf2 edge stride (floats), 128 + 4 pad
#define NCPAD  50176   // NCENT padded to 196*256

typedef __attribute__((ext_vector_type(8))) short short8;
typedef __attribute__((ext_vector_type(4))) float f32x4;

__device__ __forceinline__ unsigned short f2bf(float f) {
  union { __hip_bfloat16 h; unsigned short u; } v;
  v.h = __float2bfloat16(f);
  return v.u;
}

// Order-preserving float->uint encoding: uint compare == float compare.
// key==0 is below every encodable real value -> "-inf / untouched".
__device__ __forceinline__ unsigned encodeKey(float f) {
  unsigned u = __float_as_uint(f);
  return u ^ ((unsigned)((int)u >> 31) | 0x80000000u);
}

__device__ __forceinline__ float decodeKey(unsigned k) {
  if (k == 0u) return 0.0f;  // empty segment -> 0 (torch_scatter convention)
  unsigned u = (k & 0x80000000u) ? (k ^ 0x80000000u) : ~k;
  return __uint_as_float(u);
}

// ---------------- fused prep: cvt x->bf16, pack W1/W2, dst histogram ----
// cnt must be zeroed (memset) before this kernel runs.
// blocks: [0,3125) cvt x | [3125,3131) pack W1 | [3131,3139) pack W2
//         [3139,9389) histogram (fire-and-forget atomics)
__global__ void k_prep(const float* __restrict__ x, const float* __restrict__ W1,
                       const float* __restrict__ W2, const int* __restrict__ dst,
                       unsigned short* __restrict__ xbf, unsigned short* __restrict__ W1f,
                       unsigned short* __restrict__ W2f, int* __restrict__ cnt) {
  const int b = blockIdx.x;
  const int t = threadIdx.x;
  if (b < 3125) {                       // cvt x: 8 floats -> 8 bf16 per thread
    int i = b * 256 + t;                // 800000 threads
    const float4* xr = reinterpret_cast<const float4*>(x);
    float4 v0 = xr[2 * i], v1 = xr[2 * i + 1];
    short8 w;
    w[0] = (short)f2bf(v0.x); w[1] = (short)f2bf(v0.y);
    w[2] = (short)f2bf(v0.z); w[3] = (short)f2bf(v0.w);
    w[4] = (short)f2bf(v1.x); w[5] = (short)f2bf(v1.y);
    w[6] = (short)f2bf(v1.z); w[7] = (short)f2bf(v1.w);
    reinterpret_cast<short8*>(xbf)[i] = w;
  } else if (b < 3131) {                // pack W1 -> bf16 frags, K padded to 96
    int tid = (b - 3125) * 256 + t;     // 0..1535
    int lane = tid & 63, g = tid >> 6;
    int nt = g / 3, ks = g % 3;
    int n = nt * 16 + (lane & 15);
    int k0 = ks * 32 + (lane >> 4) * 8;
    short8 v;
    for (int j = 0; j < 8; ++j) {
      int k = k0 + j;
      float f = (k < DF + DP) ? W1[k * DH + n] : 0.0f;
      v[j] = (short)f2bf(f);
    }
    *reinterpret_cast<short8*>(W1f + (size_t)tid * 8) = v;
  } else if (b < 3139) {                // pack W2 -> bf16 frags
    int tid = (b - 3131) * 256 + t;     // 0..2047
    int lane = tid & 63, g = tid >> 6;
    int nt = g >> 2, ks = g & 3;
    int n = nt * 16 + (lane & 15);
    int k0 = ks * 32 + (lane >> 4) * 8;
    short8 v;
    for (int j = 0; j < 8; ++j) {
      int k = k0 + j;
      v[j] = (short)f2bf(W2[k * DH + n]);
    }
    *reinterpret_cast<short8*>(W2f + (size_t)tid * 8) = v;
  } else {                              // dst histogram
    int i = (b - 3139) * 256 + t;       // 1.6M threads
    atomicAdd(&cnt[dst[i]], 1);
  }
}

// ---------------- scan of cnt (exclusive, in place) ----------------

__global__ void k_s1(const int* __restrict__ cnt, int* __restrict__ bsum) {
  __shared__ int sh[256];
  int t = threadIdx.x;
  sh[t] = cnt[blockIdx.x * 256 + t];
  __syncthreads();
  for (int off = 128; off > 0; off >>= 1) {
    if (t < off) sh[t] += sh[t + off];
    __syncthreads();
  }
  if (t == 0) bsum[blockIdx.x] = sh[0];
}

__global__ void k_s2(const int* __restrict__ bsum, int* __restrict__ bbase) {
  __shared__ int sh[256];
  int t = threadIdx.x;
  int v = (t < 196) ? bsum[t] : 0;
  sh[t] = v;
  __syncthreads();
  for (int off = 1; off < 256; off <<= 1) {
    int u = (t >= off) ? sh[t - off] : 0;
    __syncthreads();
    sh[t] += u;
    __syncthreads();
  }
  if (t < 196) bbase[t] = sh[t] - v;
}

__global__ void k_s3(int* __restrict__ cnt, const int* __restrict__ bbase) {
  __shared__ int sh[256];
  int t = threadIdx.x, i = blockIdx.x * 256 + t;
  int v = cnt[i];
  sh[t] = v;
  __syncthreads();
  for (int off = 1; off < 256; off <<= 1) {
    int u = (t >= off) ? sh[t - off] : 0;
    __syncthreads();
    sh[t] += u;
    __syncthreads();
  }
  cnt[i] = sh[t] - v + bbase[blockIdx.x];
}

// place sorted packed {dst,src} records; base[] is destroyed (becomes end offsets)
__global__ void k_place(const int* __restrict__ src, const int* __restrict__ dst,
                        int* __restrict__ base, unsigned long long* __restrict__ sdS) {
  int i = blockIdx.x * 256 + threadIdx.x;
  int d = dst[i];
  int p = atomicAdd(&base[d], 1);
  sdS[p] = ((unsigned long long)(unsigned)d << 32) | (unsigned)src[i];
}

__global__ void k_decode(unsigned* __restrict__ out) {
  int i = blockIdx.x * blockDim.x + threadIdx.x;
  uint4 v = reinterpret_cast<uint4*>(out)[i];
  float4 f;
  f.x = decodeKey(v.x);
  f.y = decodeKey(v.y);
  f.z = decodeKey(v.z);
  f.w = decodeKey(v.w);
  reinterpret_cast<float4*>(out)[i] = f;
}

// Fused: gather bf16 feats (sorted order) -> GEMM1(relu) -> GEMM2 ->
// segmented max reduce in LDS (transposed score buffer, ballot boundary mask)
// -> per-segment atomicMax scatter. Single 34.8 KB LDS buffer -> 4 blocks/CU.
__global__ void __launch_bounds__(256, 4)
k_mlp(const unsigned short* __restrict__ xbf, const float* __restrict__ pos,
      const float* __restrict__ pos_c, const unsigned long long* __restrict__ sdS,
      const float* __restrict__ b1, const float* __restrict__ b2,
      const unsigned short* __restrict__ W1f, const unsigned short* __restrict__ W2f,
      unsigned* __restrict__ outU) {
  __shared__ __align__(16) unsigned short buf[TILE * LDH];  // 34816 B
  __shared__ int dstLoc[TILE];

  const int t = threadIdx.x;
  const int e0 = blockIdx.x * TILE;

  // ---- Stage A-tile into buf (LDA stride): 128 edges x 96 k bf16 (pure copy)
  {
    const int e = t >> 1, p = t & 1;
    const unsigned long long rec = sdS[e0 + e];
    const int s = (int)(rec & 0xffffffffu);
    const short8* xr = reinterpret_cast<const short8*>(xbf + (size_t)s * DF);
    for (int i = 0; i < 4; ++i)
      *reinterpret_cast<short8*>(&buf[e * LDA + p * 32 + i * 8]) = xr[p * 4 + i];
    short8 z = {0, 0, 0, 0, 0, 0, 0, 0};
    *reinterpret_cast<short8*>(&buf[e * LDA + 72 + p * 16]) = z;
    *reinterpret_cast<short8*>(&buf[e * LDA + 72 + p * 16 + 8]) = z;
  }
  if (t < TILE) {
    const unsigned long long rec = sdS[e0 + t];
    const int s = (int)(rec & 0xffffffffu);
    const int c = (int)(rec >> 32);
    dstLoc[t] = c;
    float dx = pos[(size_t)s * 3 + 0] - pos_c[(size_t)c * 3 + 0];
    float dy = pos[(size_t)s * 3 + 1] - pos_c[(size_t)c * 3 + 1];
    float dz = pos[(size_t)s * 3 + 2] - pos_c[(size_t)c * 3 + 2];
    short8 w = {0, 0, 0, 0, 0, 0, 0, 0};
    w[0] = (short)f2bf(dx); w[1] = (short)f2bf(dy); w[2] = (short)f2bf(dz);
    *reinterpret_cast<short8*>(&buf[t * LDA + 64]) = w;
  }
  __syncthreads();

  const int lane = t & 63;
  const int w = t >> 6;
  const int l16 = lane & 15;
  const int quad = lane >> 4;

  // ---- GEMM1 A-fragments into registers, then buf is free for H1
  short8 a1[2][3];
  for (int mi = 0; mi < 2; ++mi) {
    int row = (2 * w + mi) * 16 + l16;
    for (int ks = 0; ks < 3; ++ks)
      a1[mi][ks] = *reinterpret_cast<const short8*>(&buf[row * LDA + ks * 32 + quad * 8]);
  }
  __syncthreads();  // all A-frags registered; buf reusable

  // ---- GEMM1: [128 x 96] @ [96 x 128] -> relu -> H1 (bf16, LDH stride)
  for (int nt = 0; nt < 8; ++nt) {
    short8 b[3];
    for (int ks = 0; ks < 3; ++ks)
      b[ks] = *reinterpret_cast<const short8*>(W1f + ((size_t)(nt * 3 + ks) * 64 + lane) * 8);
    f32x4 acc0 = {0.f, 0.f, 0.f, 0.f}, acc1 = {0.f, 0.f, 0.f, 0.f};
    for (int ks = 0; ks < 3; ++ks) {
      acc0 = __builtin_amdgcn_mfma_f32_16x16x32_bf16(a1[0][ks], b[ks], acc0, 0, 0, 0);
      acc1 = __builtin_amdgcn_mfma_f32_16x16x32_bf16(a1[1][ks], b[ks], acc1, 0, 0, 0);
    }
    int n = nt * 16 + l16;
    float bias = b1[n];
    for (int r = 0; r < 4; ++r) {
      float v0 = acc0[r] + bias; v0 = v0 > 0.f ? v0 : 0.f;
      buf[((2 * w) * 16 + quad * 4 + r) * LDH + n] = f2bf(v0);
      float v1 = acc1[r] + bias; v1 = v1 > 0.f ? v1 : 0.f;
      buf[((2 * w + 1) * 16 + quad * 4 + r) * LDH + n] = f2bf(v1);
    }
  }
  __syncthreads();

  // ---- GEMM2 A-fragments into registers, then buf is free for Sf2
  short8 a2[2][4];
  for (int mi = 0; mi < 2; ++mi) {
    int row = (2 * w + mi) * 16 + l16;
    for (int ks = 0; ks < 4; ++ks)
      a2[mi][ks] = *reinterpret_cast<const short8*>(&buf[row * LDH + ks * 32 + quad * 8]);
  }
  __syncthreads();

  // Sf2 transposed: [col 0..63][edge 0..127], stride LDE floats (33792 B)
  float* Sf = reinterpret_cast<float*>(buf);
  const int col = t & 63;    // reduction column (n within half)
  const int chunk = t >> 6;  // 32-edge chunk (== wave id)

  // boundary bitmask for this wave's chunk (wave-uniform), bit i:
  // dst changes between edge i-1 and i within the chunk
  unsigned mask32;
  {
    int pred = 0;
    if (lane > 0 && lane < 32)
      pred = (dstLoc[chunk * 32 + lane] != dstLoc[chunk * 32 + lane - 1]) ? 1 : 0;
    mask32 = (unsigned)(__ballot(pred) & 0xffffffffull);
  }

  for (int half = 0; half < 2; ++half) {
    for (int ntl = 0; ntl < 4; ++ntl) {
      const int nt = half * 4 + ntl;
      short8 b[4];
      for (int ks = 0; ks < 4; ++ks)
        b[ks] = *reinterpret_cast<const short8*>(W2f + ((size_t)(nt * 4 + ks) * 64 + lane) * 8);
      f32x4 acc0 = {0.f, 0.f, 0.f, 0.f}, acc1 = {0.f, 0.f, 0.f, 0.f};
      for (int ks = 0; ks < 4; ++ks) {
        acc0 = __builtin_amdgcn_mfma_f32_16x16x32_bf16(a2[0][ks], b[ks], acc0, 0, 0, 0);
        acc1 = __builtin_amdgcn_mfma_f32_16x16x32_bf16(a2[1][ks], b[ks], acc1, 0, 0, 0);
      }
      const int nl = ntl * 16 + l16;  // n - half*64
      const float bias = b2[half * 64 + nl];
      for (int r = 0; r < 4; ++r) { acc0[r] += bias; acc1[r] += bias; }
      // C-layout regs r = 4 consecutive edges -> one b128 store each
      *reinterpret_cast<f32x4*>(&Sf[nl * LDE + (2 * w) * 16 + quad * 4]) = acc0;
      *reinterpret_cast<f32x4*>(&Sf[nl * LDE + (2 * w + 1) * 16 + quad * 4]) = acc1;
    }
    __syncthreads();
    // segmented max over this wave's 32 sorted edges, vectorized 4-wide
    float running = -3.402823466e38f;
    const float* row = &Sf[col * LDE + chunk * 32];
    for (int g = 0; g < 8; ++g) {
      f32x4 v = *reinterpret_cast<const f32x4*>(row + 4 * g);
      unsigned bits = (mask32 >> (4 * g)) & 0xFu;
      if (bits == 0u) {
        running = fmaxf(running, fmaxf(fmaxf(v[0], v[1]), fmaxf(v[2], v[3])));
      } else {
        for (int j = 0; j < 4; ++j) {
          if ((bits >> j) & 1u) {
            int dprev = dstLoc[chunk * 32 + 4 * g + j - 1];
            atomicMax(&outU[(size_t)dprev * DOUT + half * 64 + col], encodeKey(running));
            running = -3.402823466e38f;
          }
          running = fmaxf(running, v[j]);
        }
      }
    }
    int dlast = dstLoc[chunk * 32 + 31];
    atomicMax(&outU[(size_t)dlast * DOUT + half * 64 + col], encodeKey(running));
    __syncthreads();
  }
}

extern "C" void kernel_launch(void* const* d_in, const int* in_sizes, int n_in,
                              void* d_out, int out_size, void* d_ws, size_t ws_size,
                              hipStream_t stream) {
  const float* x     = (const float*)d_in[0];
  // d_in[1] = x_c: only shape used by reference
  const float* pos   = (const float*)d_in[2];
  const float* pos_c = (const float*)d_in[3];
  const int*   src   = (const int*)d_in[4];
  const int*   dst   = (const int*)d_in[5];
  const float* W1    = (const float*)d_in[6];
  const float* b1    = (const float*)d_in[7];
  const float* W2    = (const float*)d_in[8];
  const float* b2    = (const float*)d_in[9];
  unsigned* outU = (unsigned*)d_out;

  // workspace layout (bytes)
  char* base = (char*)d_ws;
  unsigned short* W1f = (unsigned short*)base;                    // 24576
  unsigned short* W2f = (unsigned short*)(base + 24576);          // 32768 -> 57344
  int* bsum  = (int*)(base + 57344);                              // 1024  -> 58368
  int* bbase = (int*)(base + 58368);                              // 1024  -> 59392 (pad to 65536)
  int* cnt   = (int*)(base + 65536);                              // 200704 -> 266240
  unsigned long long* sdS = (unsigned long long*)(base + 266240); // 12.8MB -> 13066240
  unsigned short* xbf = (unsigned short*)(base + 13066240);       // 12.8MB -> 25866240
  // total ~= 24.7 MB

  hipMemsetAsync(cnt, 0, NCPAD * sizeof(int), stream);
  hipMemsetAsync(outU, 0, (size_t)NCENT * DOUT * sizeof(unsigned), stream);
  k_prep<<<9389, 256, 0, stream>>>(x, W1, W2, dst, xbf, W1f, W2f, cnt);
  k_s1<<<NCPAD / 256, 256, 0, stream>>>(cnt, bsum);
  k_s2<<<1, 256, 0, stream>>>(bsum, bbase);
  k_s3<<<NCPAD / 256, 256, 0, stream>>>(cnt, bbase);
  k_place<<<NEDGE / 256, 256, 0, stream>>>(src, dst, cnt, sdS);
  k_mlp<<<NEDGE / TILE, 256, 0, stream>>>(xbf, pos, pos_c, sdS,
                                          b1, b2, W1f, W2f, outU);
  k_decode<<<(NCENT * DOUT / 4) / 256, 256, 0, stream>>>(outU);
}

// Round 6
// 384.645 us; speedup vs baseline: 1.2370x; 1.2370x over previous
//
#include <hip/hip_runtime.h>
#include <hip/hip_bf16.h>

// Problem constants (from reference)
#define NPTS   100000
#define NCENT  50000
#define NEDGE  1600000
#define DF     64      // feature dim
#define DP     3       // pos dim
#define DH     128     // hidden
#define DOUT   128     // out
#define TILE   128     // edges per block
#define LDA    104     // A-tile leading dim (ushorts), 96 + 8 pad
#define LDH    136     // H1-tile leading dim (ushorts), 128 + 8 pad
#define LDE    132     // Sf2 edge stride (floats), 128 + 4 pad
#define NCPAD  50176   // NCENT padded to 196*256

typedef __attribute__((ext_vector_type(8))) short short8;
typedef __attribute__((ext_vector_type(4))) float f32x4;

__device__ __forceinline__ unsigned short f2bf(float f) {
  union { __hip_bfloat16 h; unsigned short u; } v;
  v.h = __float2bfloat16(f);
  return v.u;
}

// Order-preserving float->uint encoding: uint compare == float compare.
// key==0 is below every encodable real value -> "-inf / untouched".
__device__ __forceinline__ unsigned encodeKey(float f) {
  unsigned u = __float_as_uint(f);
  return u ^ ((unsigned)((int)u >> 31) | 0x80000000u);
}

__device__ __forceinline__ float decodeKey(unsigned k) {
  if (k == 0u) return 0.0f;  // empty segment -> 0 (torch_scatter convention)
  unsigned u = (k & 0x80000000u) ? (k ^ 0x80000000u) : ~k;
  return __uint_as_float(u);
}

// ---------------- fused prep: init out, cvt x->bf16, zero cnt, pack W1/W2 ----
// block ranges: [0,6250) init outU | [6250,9375) cvt x | [9375,9571) zero cnt
//               [9571,9577) pack W1 | [9577,9585) pack W2
__global__ void k_prep(const float* __restrict__ x, const float* __restrict__ W1,
                       const float* __restrict__ W2, unsigned short* __restrict__ xbf,
                       unsigned short* __restrict__ W1f, unsigned short* __restrict__ W2f,
                       int* __restrict__ cnt, unsigned* __restrict__ outU) {
  const int b = blockIdx.x;
  const int t = threadIdx.x;
  if (b < 6250) {                       // init outU (6.4M uints, uint4/thread)
    int i = b * 256 + t;
    reinterpret_cast<uint4*>(outU)[i] = make_uint4(0u, 0u, 0u, 0u);
  } else if (b < 9375) {                // cvt x: 8 floats -> 8 bf16 per thread
    int i = (b - 6250) * 256 + t;       // 800000 threads
    const float4* xr = reinterpret_cast<const float4*>(x);
    float4 v0 = xr[2 * i], v1 = xr[2 * i + 1];
    short8 w;
    w[0] = (short)f2bf(v0.x); w[1] = (short)f2bf(v0.y);
    w[2] = (short)f2bf(v0.z); w[3] = (short)f2bf(v0.w);
    w[4] = (short)f2bf(v1.x); w[5] = (short)f2bf(v1.y);
    w[6] = (short)f2bf(v1.z); w[7] = (short)f2bf(v1.w);
    reinterpret_cast<short8*>(xbf)[i] = w;
  } else if (b < 9571) {                // zero cnt
    cnt[(b - 9375) * 256 + t] = 0;
  } else if (b < 9577) {                // pack W1 -> bf16 B-frags, K padded to 96
    int tid = (b - 9571) * 256 + t;     // 0..1535
    int lane = tid & 63, g = tid >> 6;
    int nt = g / 3, ks = g % 3;
    int n = nt * 16 + (lane & 15);
    int k0 = ks * 32 + (lane >> 4) * 8;
    short8 v;
    for (int j = 0; j < 8; ++j) {
      int k = k0 + j;
      float f = (k < DF + DP) ? W1[k * DH + n] : 0.0f;
      v[j] = (short)f2bf(f);
    }
    *reinterpret_cast<short8*>(W1f + (size_t)tid * 8) = v;
  } else {                              // pack W2 -> bf16 B-frags
    int tid = (b - 9577) * 256 + t;     // 0..2047
    int lane = tid & 63, g = tid >> 6;
    int nt = g >> 2, ks = g & 3;
    int n = nt * 16 + (lane & 15);
    int k0 = ks * 32 + (lane >> 4) * 8;
    short8 v;
    for (int j = 0; j < 8; ++j) {
      int k = k0 + j;
      v[j] = (short)f2bf(W2[k * DH + n]);
    }
    *reinterpret_cast<short8*>(W2f + (size_t)tid * 8) = v;
  }
}

// ---------------- counting sort by dst (ONE returning-atomic pass) ----------

// rank[i] = position of edge i within its dst group (fits in 16 bits)
__global__ void k_rank(const int* __restrict__ dst, int* __restrict__ cnt,
                       unsigned short* __restrict__ rank) {
  int i = blockIdx.x * 256 + threadIdx.x;
  rank[i] = (unsigned short)atomicAdd(&cnt[dst[i]], 1);
}

// per-256-chunk sums
__global__ void k_s1(const int* __restrict__ cnt, int* __restrict__ bsum) {
  __shared__ int sh[256];
  int t = threadIdx.x;
  sh[t] = cnt[blockIdx.x * 256 + t];
  __syncthreads();
  for (int off = 128; off > 0; off >>= 1) {
    if (t < off) sh[t] += sh[t + off];
    __syncthreads();
  }
  if (t == 0) bsum[blockIdx.x] = sh[0];
}

// exclusive scan of the 196 chunk sums (single 256-thread block)
__global__ void k_s2(const int* __restrict__ bsum, int* __restrict__ bbase) {
  __shared__ int sh[256];
  int t = threadIdx.x;
  int v = (t < 196) ? bsum[t] : 0;
  sh[t] = v;
  __syncthreads();
  for (int off = 1; off < 256; off <<= 1) {
    int u = (t >= off) ? sh[t - off] : 0;
    __syncthreads();
    sh[t] += u;
    __syncthreads();
  }
  if (t < 196) bbase[t] = sh[t] - v;
}

// in-place: cnt[i] <- exclusive prefix (global base per center)
__global__ void k_s3(int* __restrict__ cnt, const int* __restrict__ bbase) {
  __shared__ int sh[256];
  int t = threadIdx.x, i = blockIdx.x * 256 + t;
  int v = cnt[i];
  sh[t] = v;
  __syncthreads();
  for (int off = 1; off < 256; off <<= 1) {
    int u = (t >= off) ? sh[t - off] : 0;
    __syncthreads();
    sh[t] += u;
    __syncthreads();
  }
  cnt[i] = sh[t] - v + bbase[blockIdx.x];
}

// materialize sorted packed {dst,src} records -- pure reads, no atomics
__global__ void k_place(const int* __restrict__ src, const int* __restrict__ dst,
                        const int* __restrict__ base, const unsigned short* __restrict__ rank,
                        unsigned long long* __restrict__ sdS) {
  int i = blockIdx.x * 256 + threadIdx.x;
  int d = dst[i];
  int p = base[d] + (int)rank[i];
  sdS[p] = ((unsigned long long)(unsigned)d << 32) | (unsigned)src[i];
}

__global__ void k_decode(unsigned* __restrict__ out) {
  int i = blockIdx.x * blockDim.x + threadIdx.x;
  uint4 v = reinterpret_cast<uint4*>(out)[i];
  float4 f;
  f.x = decodeKey(v.x);
  f.y = decodeKey(v.y);
  f.z = decodeKey(v.z);
  f.w = decodeKey(v.w);
  reinterpret_cast<float4*>(out)[i] = f;
}

// Fused: gather bf16 feats (sorted order) -> GEMM1(relu) -> GEMM2 ->
// segmented max reduce in LDS (transposed score buffer, ballot boundary mask)
// -> per-segment atomicMax scatter. Single 34.8 KB LDS buffer -> 4 blocks/CU.
__global__ void __launch_bounds__(256, 4)
k_mlp(const unsigned short* __restrict__ xbf, const float* __restrict__ pos,
      const float* __restrict__ pos_c, const unsigned long long* __restrict__ sdS,
      const float* __restrict__ b1, const float* __restrict__ b2,
      const unsigned short* __restrict__ W1f, const unsigned short* __restrict__ W2f,
      unsigned* __restrict__ outU) {
  __shared__ __align__(16) unsigned short buf[TILE * LDH];  // 34816 B
  __shared__ int dstLoc[TILE];

  const int t = threadIdx.x;
  const int e0 = blockIdx.x * TILE;

  // ---- Stage A-tile into buf (LDA stride): 128 edges x 96 k bf16 (pure copy)
  {
    const int e = t >> 1, p = t & 1;
    const unsigned long long rec = sdS[e0 + e];
    const int s = (int)(rec & 0xffffffffu);
    const short8* xr = reinterpret_cast<const short8*>(xbf + (size_t)s * DF);
    for (int i = 0; i < 4; ++i)
      *reinterpret_cast<short8*>(&buf[e * LDA + p * 32 + i * 8]) = xr[p * 4 + i];
    short8 z = {0, 0, 0, 0, 0, 0, 0, 0};
    *reinterpret_cast<short8*>(&buf[e * LDA + 72 + p * 16]) = z;
    *reinterpret_cast<short8*>(&buf[e * LDA + 72 + p * 16 + 8]) = z;
  }
  if (t < TILE) {
    const unsigned long long rec = sdS[e0 + t];
    const int s = (int)(rec & 0xffffffffu);
    const int c = (int)(rec >> 32);
    dstLoc[t] = c;
    float dx = pos[(size_t)s * 3 + 0] - pos_c[(size_t)c * 3 + 0];
    float dy = pos[(size_t)s * 3 + 1] - pos_c[(size_t)c * 3 + 1];
    float dz = pos[(size_t)s * 3 + 2] - pos_c[(size_t)c * 3 + 2];
    short8 w = {0, 0, 0, 0, 0, 0, 0, 0};
    w[0] = (short)f2bf(dx); w[1] = (short)f2bf(dy); w[2] = (short)f2bf(dz);
    *reinterpret_cast<short8*>(&buf[t * LDA + 64]) = w;
  }
  __syncthreads();

  const int lane = t & 63;
  const int w = t >> 6;
  const int l16 = lane & 15;
  const int quad = lane >> 4;

  // ---- GEMM1 A-fragments into registers, then buf is free for H1
  short8 a1[2][3];
  for (int mi = 0; mi < 2; ++mi) {
    int row = (2 * w + mi) * 16 + l16;
    for (int ks = 0; ks < 3; ++ks)
      a1[mi][ks] = *reinterpret_cast<const short8*>(&buf[row * LDA + ks * 32 + quad * 8]);
  }
  __syncthreads();  // all A-frags registered; buf reusable

  // ---- GEMM1: [128 x 96] @ [96 x 128] -> relu -> H1 (bf16, LDH stride)
  for (int nt = 0; nt < 8; ++nt) {
    short8 b[3];
    for (int ks = 0; ks < 3; ++ks)
      b[ks] = *reinterpret_cast<const short8*>(W1f + ((size_t)(nt * 3 + ks) * 64 + lane) * 8);
    f32x4 acc0 = {0.f, 0.f, 0.f, 0.f}, acc1 = {0.f, 0.f, 0.f, 0.f};
    for (int ks = 0; ks < 3; ++ks) {
      acc0 = __builtin_amdgcn_mfma_f32_16x16x32_bf16(a1[0][ks], b[ks], acc0, 0, 0, 0);
      acc1 = __builtin_amdgcn_mfma_f32_16x16x32_bf16(a1[1][ks], b[ks], acc1, 0, 0, 0);
    }
    int n = nt * 16 + l16;
    float bias = b1[n];
    for (int r = 0; r < 4; ++r) {
      float v0 = acc0[r] + bias; v0 = v0 > 0.f ? v0 : 0.f;
      buf[((2 * w) * 16 + quad * 4 + r) * LDH + n] = f2bf(v0);
      float v1 = acc1[r] + bias; v1 = v1 > 0.f ? v1 : 0.f;
      buf[((2 * w + 1) * 16 + quad * 4 + r) * LDH + n] = f2bf(v1);
    }
  }
  __syncthreads();

  // ---- GEMM2 A-fragments into registers, then buf is free for Sf2
  short8 a2[2][4];
  for (int mi = 0; mi < 2; ++mi) {
    int row = (2 * w + mi) * 16 + l16;
    for (int ks = 0; ks < 4; ++ks)
      a2[mi][ks] = *reinterpret_cast<const short8*>(&buf[row * LDH + ks * 32 + quad * 8]);
  }
  __syncthreads();

  // Sf2 transposed: [col 0..63][edge 0..127], stride LDE floats (33792 B)
  float* Sf = reinterpret_cast<float*>(buf);
  const int col = t & 63;    // reduction column (n within half)
  const int chunk = t >> 6;  // 32-edge chunk (== wave id)

  // boundary bitmask for this wave's chunk (wave-uniform), bit i:
  // dst changes between edge i-1 and i within the chunk
  unsigned mask32;
  {
    int pred = 0;
    if (lane > 0 && lane < 32)
      pred = (dstLoc[chunk * 32 + lane] != dstLoc[chunk * 32 + lane - 1]) ? 1 : 0;
    mask32 = (unsigned)(__ballot(pred) & 0xffffffffull);
  }

  for (int half = 0; half < 2; ++half) {
    for (int ntl = 0; ntl < 4; ++ntl) {
      const int nt = half * 4 + ntl;
      short8 b[4];
      for (int ks = 0; ks < 4; ++ks)
        b[ks] = *reinterpret_cast<const short8*>(W2f + ((size_t)(nt * 4 + ks) * 64 + lane) * 8);
      f32x4 acc0 = {0.f, 0.f, 0.f, 0.f}, acc1 = {0.f, 0.f, 0.f, 0.f};
      for (int ks = 0; ks < 4; ++ks) {
        acc0 = __builtin_amdgcn_mfma_f32_16x16x32_bf16(a2[0][ks], b[ks], acc0, 0, 0, 0);
        acc1 = __builtin_amdgcn_mfma_f32_16x16x32_bf16(a2[1][ks], b[ks], acc1, 0, 0, 0);
      }
      const int nl = ntl * 16 + l16;  // n - half*64
      const float bias = b2[half * 64 + nl];
      for (int r = 0; r < 4; ++r) { acc0[r] += bias; acc1[r] += bias; }
      // C-layout regs r = 4 consecutive edges -> one b128 store each
      *reinterpret_cast<f32x4*>(&Sf[nl * LDE + (2 * w) * 16 + quad * 4]) = acc0;
      *reinterpret_cast<f32x4*>(&Sf[nl * LDE + (2 * w + 1) * 16 + quad * 4]) = acc1;
    }
    __syncthreads();
    // segmented max over this wave's 32 sorted edges, vectorized 4-wide
    float running = -3.402823466e38f;
    const float* row = &Sf[col * LDE + chunk * 32];
    for (int g = 0; g < 8; ++g) {
      f32x4 v = *reinterpret_cast<const f32x4*>(row + 4 * g);
      unsigned bits = (mask32 >> (4 * g)) & 0xFu;
      if (bits == 0u) {
        running = fmaxf(running, fmaxf(fmaxf(v[0], v[1]), fmaxf(v[2], v[3])));
      } else {
        for (int j = 0; j < 4; ++j) {
          if ((bits >> j) & 1u) {
            int dprev = dstLoc[chunk * 32 + 4 * g + j - 1];
            atomicMax(&outU[(size_t)dprev * DOUT + half * 64 + col], encodeKey(running));
            running = -3.402823466e38f;
          }
          running = fmaxf(running, v[j]);
        }
      }
    }
    int dlast = dstLoc[chunk * 32 + 31];
    atomicMax(&outU[(size_t)dlast * DOUT + half * 64 + col], encodeKey(running));
    __syncthreads();
  }
}

extern "C" void kernel_launch(void* const* d_in, const int* in_sizes, int n_in,
                              void* d_out, int out_size, void* d_ws, size_t ws_size,
                              hipStream_t stream) {
  const float* x     = (const float*)d_in[0];
  // d_in[1] = x_c: only shape used by reference
  const float* pos   = (const float*)d_in[2];
  const float* pos_c = (const float*)d_in[3];
  const int*   src   = (const int*)d_in[4];
  const int*   dst   = (const int*)d_in[5];
  const float* W1    = (const float*)d_in[6];
  const float* b1    = (const float*)d_in[7];
  const float* W2    = (const float*)d_in[8];
  const float* b2    = (const float*)d_in[9];
  unsigned* outU = (unsigned*)d_out;

  // workspace layout (bytes)
  char* base = (char*)d_ws;
  unsigned short* W1f = (unsigned short*)base;                     // 24576
  unsigned short* W2f = (unsigned short*)(base + 24576);           // 32768 -> 57344
  int* bsum  = (int*)(base + 57344);                               // 1024  -> 58368
  int* bbase = (int*)(base + 58368);                               // 1024  -> 59392 (pad to 65536)
  int* cnt   = (int*)(base + 65536);                               // 200704 -> 266240
  unsigned short* rank = (unsigned short*)(base + 266240);         // 3.2MB -> 3466240
  unsigned long long* sdS = (unsigned long long*)(base + 3466240); // 12.8MB -> 16266240
  unsigned short* xbf = (unsigned short*)(base + 16266240);        // 12.8MB -> 29066240
  // total ~= 27.7 MB

  k_prep<<<9585, 256, 0, stream>>>(x, W1, W2, xbf, W1f, W2f, cnt, outU);
  k_rank<<<NEDGE / 256, 256, 0, stream>>>(dst, cnt, rank);
  k_s1<<<NCPAD / 256, 256, 0, stream>>>(cnt, bsum);
  k_s2<<<1, 256, 0, stream>>>(bsum, bbase);
  k_s3<<<NCPAD / 256, 256, 0, stream>>>(cnt, bbase);
  k_place<<<NEDGE / 256, 256, 0, stream>>>(src, dst, cnt, rank, sdS);
  k_mlp<<<NEDGE / TILE, 256, 0, stream>>>(xbf, pos, pos_c, sdS,
                                          b1, b2, W1f, W2f, outU);
  k_decode<<<(NCENT * DOUT / 4) / 256, 256, 0, stream>>>(outU);
}

// Round 7
// 364.324 us; speedup vs baseline: 1.3060x; 1.0558x over previous
//
#include <hip/hip_runtime.h>
#include <hip/hip_bf16.h>

// Problem constants (from reference)
#define NPTS   100000
#define NCENT  50000
#define NEDGE  1600000
#define DF     64      // feature dim
#define DP     3       // pos dim
#define DH     128     // hidden
#define DOUT   128     // out
#define TILE   128     // edges per block
#define LDA    104     // A-tile leading dim (ushorts), 96 + 8 pad
#define LDH    136     // H1-tile leading dim (ushorts), 128 + 8 pad
#define LDE    132     // Sf2 edge stride (floats), 128 + 4 pad
#define NCPAD  50176   // NCENT padded to 196*256

typedef __attribute__((ext_vector_type(8))) short short8;
typedef __attribute__((ext_vector_type(4))) float f32x4;

__device__ __forceinline__ unsigned short f2bf(float f) {
  union { __hip_bfloat16 h; unsigned short u; } v;
  v.h = __float2bfloat16(f);
  return v.u;
}

// Order-preserving float->uint encoding: uint compare == float compare.
// key==0 is below every encodable real value -> "-inf / untouched".
__device__ __forceinline__ unsigned encodeKey(float f) {
  unsigned u = __float_as_uint(f);
  return u ^ ((unsigned)((int)u >> 31) | 0x80000000u);
}

__device__ __forceinline__ float decodeKey(unsigned k) {
  if (k == 0u) return 0.0f;  // empty segment -> 0 (torch_scatter convention)
  unsigned u = (k & 0x80000000u) ? (k ^ 0x80000000u) : ~k;
  return __uint_as_float(u);
}

// ---------------- fused prep + rank ----------------
// cnt must be zeroed (memset) before this kernel.
// Rank blocks FIRST so the serial sort chain starts immediately; the
// BW-bound init/cvt/pack blocks fill the machine behind them.
// blocks: [0,6250) rank | [6250,12500) init outU | [12500,15625) cvt x
//         [15625,15631) pack W1 | [15631,15639) pack W2
__global__ void k_prep(const float* __restrict__ x, const float* __restrict__ W1,
                       const float* __restrict__ W2, const int* __restrict__ dst,
                       unsigned short* __restrict__ xbf, unsigned short* __restrict__ W1f,
                       unsigned short* __restrict__ W2f, int* __restrict__ cnt,
                       unsigned short* __restrict__ rank, unsigned* __restrict__ outU) {
  const int b = blockIdx.x;
  const int t = threadIdx.x;
  if (b < 6250) {                       // rank: 1.6M returning atomics
    int i = b * 256 + t;
    rank[i] = (unsigned short)atomicAdd(&cnt[dst[i]], 1);
  } else if (b < 12500) {               // init outU (6.4M uints, uint4/thread)
    int i = (b - 6250) * 256 + t;
    reinterpret_cast<uint4*>(outU)[i] = make_uint4(0u, 0u, 0u, 0u);
  } else if (b < 15625) {               // cvt x: 8 floats -> 8 bf16 per thread
    int i = (b - 12500) * 256 + t;      // 800000 threads
    const float4* xr = reinterpret_cast<const float4*>(x);
    float4 v0 = xr[2 * i], v1 = xr[2 * i + 1];
    short8 w;
    w[0] = (short)f2bf(v0.x); w[1] = (short)f2bf(v0.y);
    w[2] = (short)f2bf(v0.z); w[3] = (short)f2bf(v0.w);
    w[4] = (short)f2bf(v1.x); w[5] = (short)f2bf(v1.y);
    w[6] = (short)f2bf(v1.z); w[7] = (short)f2bf(v1.w);
    reinterpret_cast<short8*>(xbf)[i] = w;
  } else if (b < 15631) {               // pack W1 -> bf16 B-frags, K padded to 96
    int tid = (b - 15625) * 256 + t;    // 0..1535
    int lane = tid & 63, g = tid >> 6;
    int nt = g / 3, ks = g % 3;
    int n = nt * 16 + (lane & 15);
    int k0 = ks * 32 + (lane >> 4) * 8;
    short8 v;
    for (int j = 0; j < 8; ++j) {
      int k = k0 + j;
      float f = (k < DF + DP) ? W1[k * DH + n] : 0.0f;
      v[j] = (short)f2bf(f);
    }
    *reinterpret_cast<short8*>(W1f + (size_t)tid * 8) = v;
  } else {                              // pack W2 -> bf16 B-frags
    int tid = (b - 15631) * 256 + t;    // 0..2047
    int lane = tid & 63, g = tid >> 6;
    int nt = g >> 2, ks = g & 3;
    int n = nt * 16 + (lane & 15);
    int k0 = ks * 32 + (lane >> 4) * 8;
    short8 v;
    for (int j = 0; j < 8; ++j) {
      int k = k0 + j;
      v[j] = (short)f2bf(W2[k * DH + n]);
    }
    *reinterpret_cast<short8*>(W2f + (size_t)tid * 8) = v;
  }
}

// ---------------- scan of cnt (exclusive, in place) ----------------

// per-256-chunk sums
__global__ void k_s1(const int* __restrict__ cnt, int* __restrict__ bsum) {
  __shared__ int sh[256];
  int t = threadIdx.x;
  sh[t] = cnt[blockIdx.x * 256 + t];
  __syncthreads();
  for (int off = 128; off > 0; off >>= 1) {
    if (t < off) sh[t] += sh[t + off];
    __syncthreads();
  }
  if (t == 0) bsum[blockIdx.x] = sh[0];
}

// merged s2+s3: each block computes its own exclusive prefix of bsum,
// then scans its 256-entry chunk in place
__global__ void k_s23(int* __restrict__ cnt, const int* __restrict__ bsum) {
  __shared__ int sh[256];
  __shared__ int pre;
  const int t = threadIdx.x;
  const int i = blockIdx.x * 256 + t;
  // exclusive prefix of block sums for this block
  sh[t] = (t < blockIdx.x && t < 196) ? bsum[t] : 0;
  __syncthreads();
  for (int off = 128; off > 0; off >>= 1) {
    if (t < off) sh[t] += sh[t + off];
    __syncthreads();
  }
  if (t == 0) pre = sh[0];
  __syncthreads();
  // inclusive scan of own chunk
  int v = cnt[i];
  sh[t] = v;
  __syncthreads();
  for (int off = 1; off < 256; off <<= 1) {
    int u = (t >= off) ? sh[t - off] : 0;
    __syncthreads();
    sh[t] += u;
    __syncthreads();
  }
  cnt[i] = sh[t] - v + pre;   // exclusive global base
}

// materialize sorted packed {dst,src} records -- pure reads, no atomics
__global__ void k_place(const int* __restrict__ src, const int* __restrict__ dst,
                        const int* __restrict__ base, const unsigned short* __restrict__ rank,
                        unsigned long long* __restrict__ sdS) {
  int i = blockIdx.x * 256 + threadIdx.x;
  int d = dst[i];
  int p = base[d] + (int)rank[i];
  sdS[p] = ((unsigned long long)(unsigned)d << 32) | (unsigned)src[i];
}

__global__ void k_decode(unsigned* __restrict__ out) {
  int i = blockIdx.x * blockDim.x + threadIdx.x;
  uint4 v = reinterpret_cast<uint4*>(out)[i];
  float4 f;
  f.x = decodeKey(v.x);
  f.y = decodeKey(v.y);
  f.z = decodeKey(v.z);
  f.w = decodeKey(v.w);
  reinterpret_cast<float4*>(out)[i] = f;
}

// Fused: gather bf16 feats (sorted order) -> GEMM1(relu) -> GEMM2 ->
// segmented max reduce in LDS (transposed score buffer, ballot boundary mask)
// -> per-segment atomicMax scatter. Single 34.8 KB LDS buffer -> 4 blocks/CU.
__global__ void __launch_bounds__(256, 4)
k_mlp(const unsigned short* __restrict__ xbf, const float* __restrict__ pos,
      const float* __restrict__ pos_c, const unsigned long long* __restrict__ sdS,
      const float* __restrict__ b1, const float* __restrict__ b2,
      const unsigned short* __restrict__ W1f, const unsigned short* __restrict__ W2f,
      unsigned* __restrict__ outU) {
  __shared__ __align__(16) unsigned short buf[TILE * LDH];  // 34816 B
  __shared__ int dstLoc[TILE];

  const int t = threadIdx.x;
  const int e0 = blockIdx.x * TILE;

  // ---- Stage A-tile into buf (LDA stride): 128 edges x 96 k bf16 (pure copy)
  {
    const int e = t >> 1, p = t & 1;
    const unsigned long long rec = sdS[e0 + e];
    const int s = (int)(rec & 0xffffffffu);
    const short8* xr = reinterpret_cast<const short8*>(xbf + (size_t)s * DF);
    for (int i = 0; i < 4; ++i)
      *reinterpret_cast<short8*>(&buf[e * LDA + p * 32 + i * 8]) = xr[p * 4 + i];
    short8 z = {0, 0, 0, 0, 0, 0, 0, 0};
    *reinterpret_cast<short8*>(&buf[e * LDA + 72 + p * 16]) = z;
    *reinterpret_cast<short8*>(&buf[e * LDA + 72 + p * 16 + 8]) = z;
  }
  if (t < TILE) {
    const unsigned long long rec = sdS[e0 + t];
    const int s = (int)(rec & 0xffffffffu);
    const int c = (int)(rec >> 32);
    dstLoc[t] = c;
    float dx = pos[(size_t)s * 3 + 0] - pos_c[(size_t)c * 3 + 0];
    float dy = pos[(size_t)s * 3 + 1] - pos_c[(size_t)c * 3 + 1];
    float dz = pos[(size_t)s * 3 + 2] - pos_c[(size_t)c * 3 + 2];
    short8 w = {0, 0, 0, 0, 0, 0, 0, 0};
    w[0] = (short)f2bf(dx); w[1] = (short)f2bf(dy); w[2] = (short)f2bf(dz);
    *reinterpret_cast<short8*>(&buf[t * LDA + 64]) = w;
  }
  __syncthreads();

  const int lane = t & 63;
  const int w = t >> 6;
  const int l16 = lane & 15;
  const int quad = lane >> 4;

  // ---- GEMM1 A-fragments into registers, then buf is free for H1
  short8 a1[2][3];
  for (int mi = 0; mi < 2; ++mi) {
    int row = (2 * w + mi) * 16 + l16;
    for (int ks = 0; ks < 3; ++ks)
      a1[mi][ks] = *reinterpret_cast<const short8*>(&buf[row * LDA + ks * 32 + quad * 8]);
  }
  __syncthreads();  // all A-frags registered; buf reusable

  // ---- GEMM1: [128 x 96] @ [96 x 128] -> relu -> H1 (bf16, LDH stride)
  for (int nt = 0; nt < 8; ++nt) {
    short8 b[3];
    for (int ks = 0; ks < 3; ++ks)
      b[ks] = *reinterpret_cast<const short8*>(W1f + ((size_t)(nt * 3 + ks) * 64 + lane) * 8);
    f32x4 acc0 = {0.f, 0.f, 0.f, 0.f}, acc1 = {0.f, 0.f, 0.f, 0.f};
    for (int ks = 0; ks < 3; ++ks) {
      acc0 = __builtin_amdgcn_mfma_f32_16x16x32_bf16(a1[0][ks], b[ks], acc0, 0, 0, 0);
      acc1 = __builtin_amdgcn_mfma_f32_16x16x32_bf16(a1[1][ks], b[ks], acc1, 0, 0, 0);
    }
    int n = nt * 16 + l16;
    float bias = b1[n];
    for (int r = 0; r < 4; ++r) {
      float v0 = acc0[r] + bias; v0 = v0 > 0.f ? v0 : 0.f;
      buf[((2 * w) * 16 + quad * 4 + r) * LDH + n] = f2bf(v0);
      float v1 = acc1[r] + bias; v1 = v1 > 0.f ? v1 : 0.f;
      buf[((2 * w + 1) * 16 + quad * 4 + r) * LDH + n] = f2bf(v1);
    }
  }
  __syncthreads();

  // ---- GEMM2 A-fragments into registers, then buf is free for Sf2
  short8 a2[2][4];
  for (int mi = 0; mi < 2; ++mi) {
    int row = (2 * w + mi) * 16 + l16;
    for (int ks = 0; ks < 4; ++ks)
      a2[mi][ks] = *reinterpret_cast<const short8*>(&buf[row * LDH + ks * 32 + quad * 8]);
  }
  __syncthreads();

  // Sf2 transposed: [col 0..63][edge 0..127], stride LDE floats (33792 B)
  float* Sf = reinterpret_cast<float*>(buf);
  const int col = t & 63;    // reduction column (n within half)
  const int chunk = t >> 6;  // 32-edge chunk (== wave id)

  // boundary bitmask for this wave's chunk (wave-uniform), bit i:
  // dst changes between edge i-1 and i within the chunk
  unsigned mask32;
  {
    int pred = 0;
    if (lane > 0 && lane < 32)
      pred = (dstLoc[chunk * 32 + lane] != dstLoc[chunk * 32 + lane - 1]) ? 1 : 0;
    mask32 = (unsigned)(__ballot(pred) & 0xffffffffull);
  }

  for (int half = 0; half < 2; ++half) {
    for (int ntl = 0; ntl < 4; ++ntl) {
      const int nt = half * 4 + ntl;
      short8 b[4];
      for (int ks = 0; ks < 4; ++ks)
        b[ks] = *reinterpret_cast<const short8*>(W2f + ((size_t)(nt * 4 + ks) * 64 + lane) * 8);
      f32x4 acc0 = {0.f, 0.f, 0.f, 0.f}, acc1 = {0.f, 0.f, 0.f, 0.f};
      for (int ks = 0; ks < 4; ++ks) {
        acc0 = __builtin_amdgcn_mfma_f32_16x16x32_bf16(a2[0][ks], b[ks], acc0, 0, 0, 0);
        acc1 = __builtin_amdgcn_mfma_f32_16x16x32_bf16(a2[1][ks], b[ks], acc1, 0, 0, 0);
      }
      const int nl = ntl * 16 + l16;  // n - half*64
      const float bias = b2[half * 64 + nl];
      for (int r = 0; r < 4; ++r) { acc0[r] += bias; acc1[r] += bias; }
      // C-layout regs r = 4 consecutive edges -> one b128 store each
      *reinterpret_cast<f32x4*>(&Sf[nl * LDE + (2 * w) * 16 + quad * 4]) = acc0;
      *reinterpret_cast<f32x4*>(&Sf[nl * LDE + (2 * w + 1) * 16 + quad * 4]) = acc1;
    }
    __syncthreads();
    // segmented max over this wave's 32 sorted edges, vectorized 4-wide
    float running = -3.402823466e38f;
    const float* row = &Sf[col * LDE + chunk * 32];
    for (int g = 0; g < 8; ++g) {
      f32x4 v = *reinterpret_cast<const f32x4*>(row + 4 * g);
      unsigned bits = (mask32 >> (4 * g)) & 0xFu;
      if (bits == 0u) {
        running = fmaxf(running, fmaxf(fmaxf(v[0], v[1]), fmaxf(v[2], v[3])));
      } else {
        for (int j = 0; j < 4; ++j) {
          if ((bits >> j) & 1u) {
            int dprev = dstLoc[chunk * 32 + 4 * g + j - 1];
            atomicMax(&outU[(size_t)dprev * DOUT + half * 64 + col], encodeKey(running));
            running = -3.402823466e38f;
          }
          running = fmaxf(running, v[j]);
        }
      }
    }
    int dlast = dstLoc[chunk * 32 + 31];
    atomicMax(&outU[(size_t)dlast * DOUT + half * 64 + col], encodeKey(running));
    __syncthreads();
  }
}

extern "C" void kernel_launch(void* const* d_in, const int* in_sizes, int n_in,
                              void* d_out, int out_size, void* d_ws, size_t ws_size,
                              hipStream_t stream) {
  const float* x     = (const float*)d_in[0];
  // d_in[1] = x_c: only shape used by reference
  const float* pos   = (const float*)d_in[2];
  const float* pos_c = (const float*)d_in[3];
  const int*   src   = (const int*)d_in[4];
  const int*   dst   = (const int*)d_in[5];
  const float* W1    = (const float*)d_in[6];
  const float* b1    = (const float*)d_in[7];
  const float* W2    = (const float*)d_in[8];
  const float* b2    = (const float*)d_in[9];
  unsigned* outU = (unsigned*)d_out;

  // workspace layout (bytes)
  char* base = (char*)d_ws;
  unsigned short* W1f = (unsigned short*)base;                     // 24576
  unsigned short* W2f = (unsigned short*)(base + 24576);           // 32768 -> 57344
  int* bsum  = (int*)(base + 57344);                               // 1024  -> 58368 (pad to 65536)
  int* cnt   = (int*)(base + 65536);                               // 200704 -> 266240
  unsigned short* rank = (unsigned short*)(base + 266240);         // 3.2MB -> 3466240
  unsigned long long* sdS = (unsigned long long*)(base + 3466240); // 12.8MB -> 16266240
  unsigned short* xbf = (unsigned short*)(base + 16266240);        // 12.8MB -> 29066240
  // total ~= 27.7 MB

  hipMemsetAsync(cnt, 0, NCPAD * sizeof(int), stream);
  k_prep<<<15639, 256, 0, stream>>>(x, W1, W2, dst, xbf, W1f, W2f, cnt, rank, outU);
  k_s1<<<NCPAD / 256, 256, 0, stream>>>(cnt, bsum);
  k_s23<<<NCPAD / 256, 256, 0, stream>>>(cnt, bsum);
  k_place<<<NEDGE / 256, 256, 0, stream>>>(src, dst, cnt, rank, sdS);
  k_mlp<<<NEDGE / TILE, 256, 0, stream>>>(xbf, pos, pos_c, sdS,
                                          b1, b2, W1f, W2f, outU);
  k_decode<<<(NCENT * DOUT / 4) / 256, 256, 0, stream>>>(outU);
}